// Round 6
// baseline (468.087 us; speedup 1.0000x reference)
//
#include <hip/hip_runtime.h>
#include <hip/hip_cooperative_groups.h>

namespace cg = cooperative_groups;

#define D 128
#define BN_EPS 1e-5f
#define NBUCK 512     // coarse buckets, dst>>8 (391 used at N=100K), 256 nodes/bucket
#define BSHIFT 8
#define BNODES 256    // nodes per bucket

using short8 = __attribute__((ext_vector_type(8))) short;
using floatx4 = __attribute__((ext_vector_type(4))) float;

__device__ inline unsigned short f2bf(float f) {
    unsigned u = __float_as_uint(f);
    u += 0x7fff + ((u >> 16) & 1);  // RNE
    return (unsigned short)(u >> 16);
}
__device__ inline float bf2f(unsigned short s) {
    return __uint_as_float(((unsigned)s) << 16);
}

// ---------- prep: ONE cooperative kernel for all preprocessing ----------
// 512 blocks x 512 threads (2 blocks/CU co-resident; launch_bounds caps VGPR).
// phase0 zero counters | phase1 dst-histogram + xs=bf16(x) + Wt/scv/pov |
// phase2 partition into bucket order | phase3 per-bucket counting sort ->
// offs/colidx/dinv. Replaces memset+pAwt+pB+sort (4 graph nodes) with 1.
__global__ __launch_bounds__(512, 4) void prep_kernel(
    const int* __restrict__ src, const int* __restrict__ dst, int E, int N,
    const float* __restrict__ W, const float* __restrict__ b,
    const float* __restrict__ gamma, const float* __restrict__ beta,
    const float* __restrict__ mean, const float* __restrict__ var,
    unsigned short* __restrict__ Wt, float* __restrict__ scv,
    float* __restrict__ pov, const float* __restrict__ x,
    unsigned short* __restrict__ xs, int total4,
    int* __restrict__ bucketTot, int* __restrict__ resCnt,
    int2* __restrict__ pairs, int* __restrict__ offs,
    int* __restrict__ colidx, float* __restrict__ dinv) {
    cg::grid_group grid = cg::this_grid();
    __shared__ int sb[NBUCK];
    __shared__ int lh[NBUCK];
    __shared__ int lcur[NBUCK];
    int tid = threadIdx.x;
    int bid = blockIdx.x;
    int gsz = gridDim.x;  // == NBUCK == 512
    int gt = bid * 512 + tid;

    // ---- phase 0: zero global counters ----
    if (gt < NBUCK) {
        bucketTot[gt] = 0;
        resCnt[gt] = 0;
    }
    grid.sync();

    // ---- phase 1: histogram + xs convert + Wt transpose/BN affine ----
    lh[tid] = 0;
    __syncthreads();
    for (int i = gt; i < E; i += gsz * 512)
        atomicAdd(&lh[dst[i] >> BSHIFT], 1);
    {
        const float4* x4 = (const float4*)x;
        ushort4* xs4 = (ushort4*)xs;
        for (int i = gt; i < total4; i += gsz * 512) {
            float4 f = x4[i];
            ushort4 o;
            o.x = f2bf(f.x); o.y = f2bf(f.y);
            o.z = f2bf(f.z); o.w = f2bf(f.w);
            xs4[i] = o;
        }
    }
    if (bid < 16) {
        int t = bid * 512 + tid;  // 0..8191
#pragma unroll
        for (int h = 0; h < 2; ++h) {
            int tt = t + h * 8192;
            Wt[(size_t)(tt & 127) * D + (tt >> 7)] = f2bf(W[tt]);
        }
        if (bid == 0 && tid < D) {
            float sc = gamma[tid] * rsqrtf(var[tid] + BN_EPS);
            scv[tid] = sc;
            pov[tid] = (b[tid] - mean[tid]) * sc + beta[tid];
        }
    }
    __syncthreads();
    if (lh[tid]) atomicAdd(&bucketTot[tid], lh[tid]);
    grid.sync();

    // ---- phase 2: partition edges into bucket order ----
    sb[tid] = bucketTot[tid];
    lh[tid] = 0;
    __syncthreads();
    for (int d = 1; d < NBUCK; d <<= 1) {
        int v = (tid >= d) ? sb[tid - d] : 0;
        __syncthreads();
        sb[tid] += v;
        __syncthreads();
    }
    // sb = inclusive scan; exclusive base for bucket t = sb[t] - bucketTot[t]
    int chunk = (E + gsz - 1) / gsz;
    int base = bid * chunk;
    int lim = min(chunk, E - base);
    if (lim > 0) {
        for (int i = tid; i < lim; i += 512)
            atomicAdd(&lh[dst[base + i] >> BSHIFT], 1);
        __syncthreads();
        int c = lh[tid];
        lcur[tid] = c ? (sb[tid] - bucketTot[tid]) + atomicAdd(&resCnt[tid], c) : 0;
        __syncthreads();
        for (int i = tid; i < lim; i += 512) {
            int s = src[base + i], d2 = dst[base + i];
            int pos = atomicAdd(&lcur[d2 >> BSHIFT], 1);
            pairs[pos] = make_int2(s, d2);
        }
    }
    grid.sync();

    // ---- phase 3: per-bucket counting sort (block bid <-> bucket bid) ----
    // sb (inclusive scan) still valid in LDS from phase 2.
    int cnt = bucketTot[bid];
    int bbase = sb[bid] - cnt;
    if (tid < BNODES) lh[tid] = 0;
    __syncthreads();
    for (int i = tid; i < cnt; i += 512)
        atomicAdd(&lh[pairs[bbase + i].y & (BNODES - 1)], 1);
    __syncthreads();
    int orig = (tid < BNODES) ? lh[tid] : 0;
    for (int d = 1; d < BNODES; d <<= 1) {
        int v = (tid < BNODES && tid >= d) ? lh[tid - d] : 0;
        __syncthreads();
        if (tid < BNODES) lh[tid] += v;
        __syncthreads();
    }
    if (tid < BNODES) {
        int exc = lh[tid] - orig;
        int node = bid * BNODES + tid;
        if (node < N) {
            offs[node] = bbase + exc;
            dinv[node] = rsqrtf((float)(orig + 1));
        }
        lcur[tid] = exc;
    }
    if (bid == 0 && tid == 0) offs[N] = E;
    __syncthreads();
    for (int i = tid; i < cnt; i += 512) {
        int2 p = pairs[bbase + i];
        int pos = atomicAdd(&lcur[p.y & (BNODES - 1)], 1);
        colidx[bbase + pos] = p.x;
    }
}

// ---------- fallback kernels (small-ws path) ----------
__global__ void wt_kernel(const float* __restrict__ W, const float* __restrict__ b,
                          const float* __restrict__ gamma, const float* __restrict__ beta,
                          const float* __restrict__ mean, const float* __restrict__ var,
                          unsigned short* __restrict__ Wt, float* __restrict__ scv,
                          float* __restrict__ pov) {
    int t = blockIdx.x * blockDim.x + threadIdx.x;
    int k = t >> 7, n = t & 127;
    Wt[(size_t)n * D + k] = f2bf(W[t]);
    if (t < D) {
        float sc = gamma[t] * rsqrtf(var[t] + BN_EPS);
        scv[t] = sc;
        pov[t] = (b[t] - mean[t]) * sc + beta[t];
    }
}

__global__ void deg_kernel(const int* __restrict__ dst, int* __restrict__ deg, int E) {
    int e = blockIdx.x * blockDim.x + threadIdx.x;
    if (e < E) atomicAdd(&deg[dst[e]], 1);
}

__global__ void dinv_kernel(const int* __restrict__ deg, float* __restrict__ dinv, int N) {
    int v = blockIdx.x * blockDim.x + threadIdx.x;
    if (v < N) dinv[v] = rsqrtf((float)(deg[v] + 1));
}

__global__ __launch_bounds__(256) void scan1_kernel(const int* __restrict__ deg,
                                                    int* __restrict__ bsum, int N) {
    __shared__ int s[256];
    int t = threadIdx.x;
    int v = blockIdx.x * 256 + t;
    s[t] = (v < N) ? deg[v] : 0;
    for (int st = 128; st > 0; st >>= 1) {
        __syncthreads();
        if (t < st) s[t] += s[t + st];
    }
    if (t == 0) bsum[blockIdx.x] = s[0];
}

__global__ __launch_bounds__(512) void scan2_kernel(int* __restrict__ bsum,
                                                    int* __restrict__ offs, int P, int N) {
    __shared__ int a[512];
    int t = threadIdx.x;
    int orig = (t < P) ? bsum[t] : 0;
    a[t] = orig;
    __syncthreads();
    for (int d = 1; d < 512; d <<= 1) {
        int tv = (t >= d) ? a[t - d] : 0;
        __syncthreads();
        a[t] += tv;
        __syncthreads();
    }
    if (t < P) bsum[t] = a[t] - orig;
    if (t == 0) offs[N] = a[511];
}

__global__ __launch_bounds__(256) void scan3_kernel(const int* __restrict__ deg,
                                                    const int* __restrict__ bsum,
                                                    int* __restrict__ offs,
                                                    int* __restrict__ cursor, int N) {
    __shared__ int a[256];
    int t = threadIdx.x;
    int v = blockIdx.x * 256 + t;
    int d = (v < N) ? deg[v] : 0;
    a[t] = d;
    __syncthreads();
    for (int st = 1; st < 256; st <<= 1) {
        int tv = (t >= st) ? a[t - st] : 0;
        __syncthreads();
        a[t] += tv;
        __syncthreads();
    }
    if (v < N) {
        int off = bsum[blockIdx.x] + a[t] - d;
        offs[v] = off;
        cursor[v] = off;
    }
}

__global__ void fill_kernel(const int* __restrict__ src, const int* __restrict__ dst,
                            int* __restrict__ cursor, int* __restrict__ colidx, int E) {
    int e = blockIdx.x * blockDim.x + threadIdx.x;
    if (e < E) {
        int d = dst[e];
        int pos = atomicAdd(&cursor[d], 1);
        colidx[pos] = src[e];
    }
}

// ---------- gather-aggregate: one wave/node, lane = 2 packed cols ----------
// Fast path: xs is bf16(x) WITHOUT dinv; apply dinv[u] per neighbor (fma).
// dinv is 400KB -> L2-resident; adds ~6MB FETCH (measured round 5).
__global__ __launch_bounds__(256) void agg_kernel(
    const float* __restrict__ x, const unsigned short* __restrict__ xs,
    const float* __restrict__ dinv, const int* __restrict__ offs,
    const int* __restrict__ colidx, float* __restrict__ outp,
    unsigned int* __restrict__ aggb, int N) {
    int wid = (blockIdx.x * blockDim.x + threadIdx.x) >> 6;
    if (wid >= N) return;
    int lane = threadIdx.x & 63;
    float dv = dinv[wid];
    float a0, a1;
    int p = offs[wid], pe = offs[wid + 1];
    if (xs) {
        const unsigned int* xs32 = (const unsigned int*)xs;
        unsigned int sv = xs32[(size_t)wid * 64 + lane];
        a0 = dv * bf2f((unsigned short)sv);
        a1 = dv * bf2f((unsigned short)(sv >> 16));
        for (; p + 16 <= pe; p += 16) {
            int u[16];
            float du[16];
            unsigned int v[16];
#pragma unroll
            for (int j = 0; j < 16; ++j) u[j] = colidx[p + j];
#pragma unroll
            for (int j = 0; j < 16; ++j) v[j] = xs32[(size_t)u[j] * 64 + lane];
#pragma unroll
            for (int j = 0; j < 16; ++j) du[j] = dinv[u[j]];
#pragma unroll
            for (int j = 0; j < 16; ++j) {
                a0 = fmaf(du[j], bf2f((unsigned short)v[j]), a0);
                a1 = fmaf(du[j], bf2f((unsigned short)(v[j] >> 16)), a1);
            }
        }
        for (; p + 4 <= pe; p += 4) {
            int u[4];
            float du[4];
            unsigned int v[4];
#pragma unroll
            for (int j = 0; j < 4; ++j) u[j] = colidx[p + j];
#pragma unroll
            for (int j = 0; j < 4; ++j) v[j] = xs32[(size_t)u[j] * 64 + lane];
#pragma unroll
            for (int j = 0; j < 4; ++j) du[j] = dinv[u[j]];
#pragma unroll
            for (int j = 0; j < 4; ++j) {
                a0 = fmaf(du[j], bf2f((unsigned short)v[j]), a0);
                a1 = fmaf(du[j], bf2f((unsigned short)(v[j] >> 16)), a1);
            }
        }
        for (; p < pe; ++p) {
            int u = colidx[p];
            float du = dinv[u];
            unsigned int v = xs32[(size_t)u * 64 + lane];
            a0 = fmaf(du, bf2f((unsigned short)v), a0);
            a1 = fmaf(du, bf2f((unsigned short)(v >> 16)), a1);
        }
        aggb[(size_t)wid * 64 + lane] =
            (unsigned int)f2bf(dv * a0) | ((unsigned int)f2bf(dv * a1) << 16);
    } else {
        const float2* x2 = (const float2*)x;
        float2 s = x2[(size_t)wid * 64 + lane];
        a0 = dv * s.x;
        a1 = dv * s.y;
        for (; p < pe; ++p) {
            int u = colidx[p];
            float du = dinv[u];
            float2 vv = x2[(size_t)u * 64 + lane];
            a0 += du * vv.x;
            a1 += du * vv.y;
        }
        float2 r;
        r.x = dv * a0;
        r.y = dv * a1;
        ((float2*)outp)[(size_t)wid * 64 + lane] = r;
    }
}

// ---------- MFMA GEMM: out = relu(BN(agg @ W + b)) + x ----------
// Wt staged once per block in LDS (32KB), XOR-swizzled -> conflict-free
// ds_read_b128 B-fragments. aggb bf16 path (fast) / fp32 outp path (fallback).
__global__ __launch_bounds__(256) void gemm_kernel(
    float* __restrict__ outp, const float* __restrict__ xg,
    const unsigned short* __restrict__ Wt, const unsigned short* __restrict__ aggb,
    const float* __restrict__ scv, const float* __restrict__ pov, int nTiles) {
    __shared__ uint4 sW4[2048];  // 32KB: [row 0..127][c4 0..15] swizzled c4^=(row&7)
    int tid = threadIdx.x;
    const uint4* W4 = (const uint4*)Wt;
#pragma unroll
    for (int i = 0; i < 8; ++i) {
        int q = tid + i * 256;  // uint4 index 0..2047
        int row = q >> 4, c4 = q & 15;
        sW4[row * 16 + (c4 ^ (row & 7))] = W4[q];
    }
    __syncthreads();

    int wid = (blockIdx.x * blockDim.x + tid) >> 6;
    if (wid >= nTiles) return;
    int lane = tid & 63;
    int m = lane & 15, quad = lane >> 4;
    int row0 = wid * 16;

    short8 A[4];
    if (aggb) {
        const unsigned short* arow = aggb + (size_t)(row0 + m) * D;
#pragma unroll
        for (int ks = 0; ks < 4; ++ks)
            A[ks] = *(const short8*)&arow[ks * 32 + quad * 8];
    } else {
        const float* arow = outp + (size_t)(row0 + m) * D;
#pragma unroll
        for (int ks = 0; ks < 4; ++ks) {
            float4 f0 = *(const float4*)(arow + ks * 32 + quad * 8);
            float4 f1 = *(const float4*)(arow + ks * 32 + quad * 8 + 4);
            short8 af;
            af[0] = (short)f2bf(f0.x); af[1] = (short)f2bf(f0.y);
            af[2] = (short)f2bf(f0.z); af[3] = (short)f2bf(f0.w);
            af[4] = (short)f2bf(f1.x); af[5] = (short)f2bf(f1.y);
            af[6] = (short)f2bf(f1.z); af[7] = (short)f2bf(f1.w);
            A[ks] = af;
        }
    }

#pragma unroll
    for (int cg2 = 0; cg2 < 8; ++cg2) {
        int brow = cg2 * 16 + m;
        floatx4 acc = {0.f, 0.f, 0.f, 0.f};
#pragma unroll
        for (int ks = 0; ks < 4; ++ks) {
            short8 Bf = *(const short8*)&sW4[brow * 16 + ((ks * 4 + quad) ^ (m & 7))];
            acc = __builtin_amdgcn_mfma_f32_16x16x32_bf16(A[ks], Bf, acc, 0, 0, 0);
        }
        int col = cg2 * 16 + m;
        float sc = scv[col], po = pov[col];
#pragma unroll
        for (int i = 0; i < 4; ++i) {
            int row = row0 + quad * 4 + i;
            float bn = acc[i] * sc + po;
            size_t idx = (size_t)row * D + col;
            outp[idx] = fmaxf(bn, 0.f) + xg[idx];
        }
    }
}

extern "C" void kernel_launch(void* const* d_in, const int* in_sizes, int n_in,
                              void* d_out, int out_size, void* d_ws, size_t ws_size,
                              hipStream_t stream) {
    const float* x = (const float*)d_in[0];
    const int* edge = (const int*)d_in[1];
    const float* Wm = (const float*)d_in[2];
    const float* b = (const float*)d_in[3];
    const float* gamma = (const float*)d_in[4];
    const float* beta = (const float*)d_in[5];
    const float* mean = (const float*)d_in[6];
    const float* var = (const float*)d_in[7];
    float* out = (float*)d_out;

    int N = in_sizes[0] / D;
    int E = in_sizes[1] / 2;
    const int* src = edge;
    const int* dst = edge + E;
    int P = (N + 255) / 256;

    // ---- workspace layout ----
    char* w = (char*)d_ws;
    size_t cur = 0;
    auto take = [&](size_t bytes) -> void* {
        cur = (cur + 15) & ~(size_t)15;
        void* p = w + cur;
        cur += bytes;
        return p;
    };
    int* deg = (int*)take((size_t)N * 4);
    int* bucketTot = (int*)take(NBUCK * 4);
    int* resCnt = (int*)take(NBUCK * 4);
    float* dinv = (float*)take((size_t)N * 4);
    int* offs = (int*)take((size_t)(N + 1) * 4);
    int* cursor = (int*)take((size_t)N * 4);
    int* bsum = (int*)take((size_t)(P + 1) * 4);
    unsigned short* Wt = (unsigned short*)take((size_t)D * D * 2);
    float* scv = (float*)take(D * 4);
    float* pov = (float*)take(D * 4);
    int* colidx = (int*)take((size_t)E * 4);
    cur = (cur + 15) & ~(size_t)15;
    size_t fixedEnd = cur;

    size_t xsBytes = (size_t)N * D * 2;
    size_t zoneBytes = (xsBytes > (size_t)E * 8) ? xsBytes : (size_t)E * 8;
    bool fast = fixedEnd + xsBytes + zoneBytes <= ws_size;

    unsigned short* xs = nullptr;
    int2* pairs = nullptr;
    unsigned int* aggb = nullptr;
    if (fast) {
        xs = (unsigned short*)(w + fixedEnd);
        pairs = (int2*)(w + fixedEnd + xsBytes);        // dead after prep phase 3
        aggb = (unsigned int*)(w + fixedEnd + xsBytes); // aliases pairs
    }

    if (fast) {
        int total4 = N * 32;
        void* args[] = {
            (void*)&src, (void*)&dst, (void*)&E, (void*)&N,
            (void*)&Wm, (void*)&b, (void*)&gamma, (void*)&beta,
            (void*)&mean, (void*)&var, (void*)&Wt, (void*)&scv,
            (void*)&pov, (void*)&x, (void*)&xs, (void*)&total4,
            (void*)&bucketTot, (void*)&resCnt, (void*)&pairs,
            (void*)&offs, (void*)&colidx, (void*)&dinv};
        hipLaunchCooperativeKernel((const void*)prep_kernel, dim3(NBUCK), dim3(512),
                                   args, 0, stream);
        agg_kernel<<<(N * 64 + 255) / 256, 256, 0, stream>>>(x, xs, dinv, offs, colidx,
                                                             out, aggb, N);
        int nTiles = (N + 15) / 16;
        gemm_kernel<<<(nTiles * 64 + 255) / 256, 256, 0, stream>>>(
            out, x, Wt, (const unsigned short*)aggb, scv, pov, nTiles);
    } else {
        wt_kernel<<<(D * D) / 256, 256, 0, stream>>>(Wm, b, gamma, beta, mean, var, Wt,
                                                     scv, pov);
        hipMemsetAsync(deg, 0, sizeof(int) * N, stream);
        deg_kernel<<<(E + 255) / 256, 256, 0, stream>>>(dst, deg, E);
        dinv_kernel<<<(N + 255) / 256, 256, 0, stream>>>(deg, dinv, N);
        scan1_kernel<<<P, 256, 0, stream>>>(deg, bsum, N);
        scan2_kernel<<<1, 512, 0, stream>>>(bsum, offs, P, N);
        scan3_kernel<<<P, 256, 0, stream>>>(deg, bsum, offs, cursor, N);
        fill_kernel<<<(E + 255) / 256, 256, 0, stream>>>(src, dst, cursor, colidx, E);
        agg_kernel<<<(N * 64 + 255) / 256, 256, 0, stream>>>(x, nullptr, dinv, offs,
                                                             colidx, out, nullptr, N);
        int nTiles = (N + 15) / 16;
        gemm_kernel<<<(nTiles * 64 + 255) / 256, 256, 0, stream>>>(out, x, Wt, nullptr,
                                                                   scv, pov, nTiles);
    }
}

// Round 7
// 356.839 us; speedup vs baseline: 1.3118x; 1.3118x over previous
//
#include <hip/hip_runtime.h>

#define D 128
#define BN_EPS 1e-5f
#define KSLOT 64      // slot capacity per node; P(deg>64 | Poisson(16)) ~ 1e-15

using short8 = __attribute__((ext_vector_type(8))) short;
using floatx4 = __attribute__((ext_vector_type(4))) float;

__device__ inline unsigned short f2bf(float f) {
    unsigned u = __float_as_uint(f);
    u += 0x7fff + ((u >> 16) & 1);  // RNE
    return (unsigned short)(u >> 16);
}
__device__ inline float bf2f(unsigned short s) {
    return __uint_as_float(((unsigned)s) << 16);
}

// ---------- initxs: zero cnt + xs=bf16(x) + Wt transpose + BN affine ----------
// One grid-stride kernel replaces memset + wt prep. 1024x256 = 256K threads.
__global__ __launch_bounds__(256) void initxs_kernel(
    const float* __restrict__ x, const float* __restrict__ W,
    const float* __restrict__ b, const float* __restrict__ gamma,
    const float* __restrict__ beta, const float* __restrict__ mean,
    const float* __restrict__ var, unsigned short* __restrict__ Wt,
    float* __restrict__ scv, float* __restrict__ pov, int* __restrict__ cnt,
    unsigned short* __restrict__ xs, int N, int total4) {
    int gt = blockIdx.x * 256 + threadIdx.x;
    int gsz = gridDim.x * 256;
    for (int i = gt; i < N; i += gsz) cnt[i] = 0;
    const float4* x4 = (const float4*)x;
    ushort4* xs4 = (ushort4*)xs;
    for (int i = gt; i < total4; i += gsz) {
        float4 f = x4[i];
        ushort4 o;
        o.x = f2bf(f.x); o.y = f2bf(f.y);
        o.z = f2bf(f.z); o.w = f2bf(f.w);
        xs4[i] = o;
    }
    if (gt < D * D)  // single shot: gsz(256K) > 16384
        Wt[(size_t)(gt & 127) * D + (gt >> 7)] = f2bf(W[gt]);
    if (gt < D) {
        float sc = gamma[gt] * rsqrtf(var[gt] + BN_EPS);
        scv[gt] = sc;
        pov[gt] = (b[gt] - mean[gt]) * sc + beta[gt];
    }
}

// ---------- fill: direct binning, replaces hist+partition+sort ----------
// pos = atomicAdd(cnt[dst]); slots[dst*64+pos] = src. cnt ends as exact deg;
// overflow (deg>64) edges are dropped here and recovered by agg's full-scan.
__global__ void fill2_kernel(const int* __restrict__ src, const int* __restrict__ dst,
                             int* __restrict__ cnt, int* __restrict__ slots, int E) {
    int e = blockIdx.x * blockDim.x + threadIdx.x;
    if (e < E) {
        int d = dst[e];
        int pos = atomicAdd(&cnt[d], 1);
        if (pos < KSLOT) slots[(size_t)d * KSLOT + pos] = src[e];
    }
}

// ---------- dinv from exact deg ----------
__global__ void dinv_kernel(const int* __restrict__ deg, float* __restrict__ dinv, int N) {
    int v = blockIdx.x * blockDim.x + threadIdx.x;
    if (v < N) dinv[v] = rsqrtf((float)(deg[v] + 1));
}

// ---------- fallback kernels (small-ws path) ----------
__global__ void wt_kernel(const float* __restrict__ W, const float* __restrict__ b,
                          const float* __restrict__ gamma, const float* __restrict__ beta,
                          const float* __restrict__ mean, const float* __restrict__ var,
                          unsigned short* __restrict__ Wt, float* __restrict__ scv,
                          float* __restrict__ pov) {
    int t = blockIdx.x * blockDim.x + threadIdx.x;
    int k = t >> 7, n = t & 127;
    Wt[(size_t)n * D + k] = f2bf(W[t]);
    if (t < D) {
        float sc = gamma[t] * rsqrtf(var[t] + BN_EPS);
        scv[t] = sc;
        pov[t] = (b[t] - mean[t]) * sc + beta[t];
    }
}

__global__ void deg_kernel(const int* __restrict__ dst, int* __restrict__ deg, int E) {
    int e = blockIdx.x * blockDim.x + threadIdx.x;
    if (e < E) atomicAdd(&deg[dst[e]], 1);
}

__global__ __launch_bounds__(256) void scan1_kernel(const int* __restrict__ deg,
                                                    int* __restrict__ bsum, int N) {
    __shared__ int s[256];
    int t = threadIdx.x;
    int v = blockIdx.x * 256 + t;
    s[t] = (v < N) ? deg[v] : 0;
    for (int st = 128; st > 0; st >>= 1) {
        __syncthreads();
        if (t < st) s[t] += s[t + st];
    }
    if (t == 0) bsum[blockIdx.x] = s[0];
}

__global__ __launch_bounds__(512) void scan2_kernel(int* __restrict__ bsum,
                                                    int* __restrict__ offs, int P, int N) {
    __shared__ int a[512];
    int t = threadIdx.x;
    int orig = (t < P) ? bsum[t] : 0;
    a[t] = orig;
    __syncthreads();
    for (int d = 1; d < 512; d <<= 1) {
        int tv = (t >= d) ? a[t - d] : 0;
        __syncthreads();
        a[t] += tv;
        __syncthreads();
    }
    if (t < P) bsum[t] = a[t] - orig;
    if (t == 0) offs[N] = a[511];
}

__global__ __launch_bounds__(256) void scan3_kernel(const int* __restrict__ deg,
                                                    const int* __restrict__ bsum,
                                                    int* __restrict__ offs,
                                                    int* __restrict__ cursor, int N) {
    __shared__ int a[256];
    int t = threadIdx.x;
    int v = blockIdx.x * 256 + t;
    int d = (v < N) ? deg[v] : 0;
    a[t] = d;
    __syncthreads();
    for (int st = 1; st < 256; st <<= 1) {
        int tv = (t >= st) ? a[t - st] : 0;
        __syncthreads();
        a[t] += tv;
        __syncthreads();
    }
    if (v < N) {
        int off = bsum[blockIdx.x] + a[t] - d;
        offs[v] = off;
        cursor[v] = off;
    }
}

__global__ void fill_kernel(const int* __restrict__ src, const int* __restrict__ dst,
                            int* __restrict__ cursor, int* __restrict__ colidx, int E) {
    int e = blockIdx.x * blockDim.x + threadIdx.x;
    if (e < E) {
        int d = dst[e];
        int pos = atomicAdd(&cursor[d], 1);
        colidx[pos] = src[e];
    }
}

__global__ __launch_bounds__(256) void agg_kernel(
    const float* __restrict__ x, const float* __restrict__ dinv,
    const int* __restrict__ offs, const int* __restrict__ colidx,
    float* __restrict__ outp, int N) {
    int wid = (blockIdx.x * blockDim.x + threadIdx.x) >> 6;
    if (wid >= N) return;
    int lane = threadIdx.x & 63;
    float dv = dinv[wid];
    int p = offs[wid], pe = offs[wid + 1];
    const float2* x2 = (const float2*)x;
    float2 s = x2[(size_t)wid * 64 + lane];
    float a0 = dv * s.x;
    float a1 = dv * s.y;
    for (; p < pe; ++p) {
        int u = colidx[p];
        float du = dinv[u];
        float2 vv = x2[(size_t)u * 64 + lane];
        a0 += du * vv.x;
        a1 += du * vv.y;
    }
    float2 r;
    r.x = dv * a0;
    r.y = dv * a1;
    ((float2*)outp)[(size_t)wid * 64 + lane] = r;
}

// ---------- gather-aggregate (fast path): slots + fp32 out ----------
// One wave/node, lane = 2 packed bf16 cols. dinv applied per neighbor (fma;
// dinv is 400KB L2-resident — measured ~free in R5/R6). Writes fp32 to out
// (gemm reads it in place) so no aggb buffer and ws footprint == old layout.
// deg>64: full edge scan (correct; never triggers at Poisson(16)).
__global__ __launch_bounds__(256) void agg2_kernel(
    const unsigned short* __restrict__ xs, const float* __restrict__ dinv,
    const int* __restrict__ cnt, const int* __restrict__ slots,
    const int* __restrict__ src, const int* __restrict__ dst,
    float* __restrict__ outp, int N, int E) {
    int wid = (blockIdx.x * blockDim.x + threadIdx.x) >> 6;
    if (wid >= N) return;
    int lane = threadIdx.x & 63;
    float dv = dinv[wid];
    const unsigned int* xs32 = (const unsigned int*)xs;
    unsigned int sv = xs32[(size_t)wid * 64 + lane];
    float a0 = dv * bf2f((unsigned short)sv);
    float a1 = dv * bf2f((unsigned short)(sv >> 16));
    int deg = cnt[wid];
    if (deg <= KSLOT) {
        const int* row = slots + (size_t)wid * KSLOT;
        int p = 0;
        for (; p + 16 <= deg; p += 16) {
            int u[16];
            float du[16];
            unsigned int v[16];
#pragma unroll
            for (int j = 0; j < 16; ++j) u[j] = row[p + j];
#pragma unroll
            for (int j = 0; j < 16; ++j) v[j] = xs32[(size_t)u[j] * 64 + lane];
#pragma unroll
            for (int j = 0; j < 16; ++j) du[j] = dinv[u[j]];
#pragma unroll
            for (int j = 0; j < 16; ++j) {
                a0 = fmaf(du[j], bf2f((unsigned short)v[j]), a0);
                a1 = fmaf(du[j], bf2f((unsigned short)(v[j] >> 16)), a1);
            }
        }
        for (; p + 4 <= deg; p += 4) {
            int u[4];
            float du[4];
            unsigned int v[4];
#pragma unroll
            for (int j = 0; j < 4; ++j) u[j] = row[p + j];
#pragma unroll
            for (int j = 0; j < 4; ++j) v[j] = xs32[(size_t)u[j] * 64 + lane];
#pragma unroll
            for (int j = 0; j < 4; ++j) du[j] = dinv[u[j]];
#pragma unroll
            for (int j = 0; j < 4; ++j) {
                a0 = fmaf(du[j], bf2f((unsigned short)v[j]), a0);
                a1 = fmaf(du[j], bf2f((unsigned short)(v[j] >> 16)), a1);
            }
        }
        for (; p < deg; ++p) {
            int u = row[p];
            float du = dinv[u];
            unsigned int v = xs32[(size_t)u * 64 + lane];
            a0 = fmaf(du, bf2f((unsigned short)v), a0);
            a1 = fmaf(du, bf2f((unsigned short)(v >> 16)), a1);
        }
    } else {
        // overflow: recompute this node from the raw edge list (slots partial)
        for (int e = 0; e < E; ++e) {
            if (dst[e] == wid) {
                int u = src[e];
                float du = dinv[u];
                unsigned int v = xs32[(size_t)u * 64 + lane];
                a0 = fmaf(du, bf2f((unsigned short)v), a0);
                a1 = fmaf(du, bf2f((unsigned short)(v >> 16)), a1);
            }
        }
    }
    float2 r;
    r.x = dv * a0;
    r.y = dv * a1;
    ((float2*)outp)[(size_t)wid * 64 + lane] = r;
}

// ---------- MFMA GEMM: out = relu(BN(out_fp32 @ W + b)) + x, in place ----------
// Wt staged once per block in LDS (32KB), XOR-swizzled -> conflict-free
// ds_read_b128 B-fragments. Per-tile in-place safe: each wave reads its own
// 16 rows fully before writing them.
__global__ __launch_bounds__(256) void gemm_kernel(
    float* __restrict__ outp, const float* __restrict__ xg,
    const unsigned short* __restrict__ Wt, const float* __restrict__ scv,
    const float* __restrict__ pov, int nTiles) {
    __shared__ uint4 sW4[2048];  // 32KB: [row 0..127][c4 0..15] swizzled c4^=(row&7)
    int tid = threadIdx.x;
    const uint4* W4 = (const uint4*)Wt;
#pragma unroll
    for (int i = 0; i < 8; ++i) {
        int q = tid + i * 256;  // uint4 index 0..2047
        int row = q >> 4, c4 = q & 15;
        sW4[row * 16 + (c4 ^ (row & 7))] = W4[q];
    }
    __syncthreads();

    int wid = (blockIdx.x * blockDim.x + tid) >> 6;
    if (wid >= nTiles) return;
    int lane = tid & 63;
    int m = lane & 15, quad = lane >> 4;
    int row0 = wid * 16;

    short8 A[4];
    const float* arow = outp + (size_t)(row0 + m) * D;
#pragma unroll
    for (int ks = 0; ks < 4; ++ks) {
        float4 f0 = *(const float4*)(arow + ks * 32 + quad * 8);
        float4 f1 = *(const float4*)(arow + ks * 32 + quad * 8 + 4);
        short8 af;
        af[0] = (short)f2bf(f0.x); af[1] = (short)f2bf(f0.y);
        af[2] = (short)f2bf(f0.z); af[3] = (short)f2bf(f0.w);
        af[4] = (short)f2bf(f1.x); af[5] = (short)f2bf(f1.y);
        af[6] = (short)f2bf(f1.z); af[7] = (short)f2bf(f1.w);
        A[ks] = af;
    }

#pragma unroll
    for (int cg2 = 0; cg2 < 8; ++cg2) {
        int brow = cg2 * 16 + m;
        floatx4 acc = {0.f, 0.f, 0.f, 0.f};
#pragma unroll
        for (int ks = 0; ks < 4; ++ks) {
            short8 Bf = *(const short8*)&sW4[brow * 16 + ((ks * 4 + quad) ^ (m & 7))];
            acc = __builtin_amdgcn_mfma_f32_16x16x32_bf16(A[ks], Bf, acc, 0, 0, 0);
        }
        int col = cg2 * 16 + m;
        float sc = scv[col], po = pov[col];
#pragma unroll
        for (int i = 0; i < 4; ++i) {
            int row = row0 + quad * 4 + i;
            float bn = acc[i] * sc + po;
            size_t idx = (size_t)row * D + col;
            outp[idx] = fmaxf(bn, 0.f) + xg[idx];
        }
    }
}

extern "C" void kernel_launch(void* const* d_in, const int* in_sizes, int n_in,
                              void* d_out, int out_size, void* d_ws, size_t ws_size,
                              hipStream_t stream) {
    const float* x = (const float*)d_in[0];
    const int* edge = (const int*)d_in[1];
    const float* Wm = (const float*)d_in[2];
    const float* b = (const float*)d_in[3];
    const float* gamma = (const float*)d_in[4];
    const float* beta = (const float*)d_in[5];
    const float* mean = (const float*)d_in[6];
    const float* var = (const float*)d_in[7];
    float* out = (float*)d_out;

    int N = in_sizes[0] / D;
    int E = in_sizes[1] / 2;
    const int* src = edge;
    const int* dst = edge + E;
    int P = (N + 255) / 256;

    // ---- workspace layout ----
    char* w = (char*)d_ws;
    size_t cur = 0;
    auto take = [&](size_t bytes) -> void* {
        cur = (cur + 15) & ~(size_t)15;
        void* p = w + cur;
        cur += bytes;
        return p;
    };
    int* deg = (int*)take((size_t)N * 4);  // == cnt in fast path
    float* dinv = (float*)take((size_t)N * 4);
    int* offs = (int*)take((size_t)(N + 1) * 4);
    int* cursor = (int*)take((size_t)N * 4);
    int* bsum = (int*)take((size_t)(P + 1) * 4);
    unsigned short* Wt = (unsigned short*)take((size_t)D * D * 2);
    float* scv = (float*)take(D * 4);
    float* pov = (float*)take(D * 4);
    int* colidx = (int*)take((size_t)E * 4);  // fallback only
    cur = (cur + 15) & ~(size_t)15;
    size_t fixedEnd = cur;

    size_t xsBytes = (size_t)N * D * 2;
    size_t slotsBytes = (size_t)N * KSLOT * 4;
    bool fast = fixedEnd + xsBytes + slotsBytes <= ws_size;

    unsigned short* xs = nullptr;
    int* slots = nullptr;
    if (fast) {
        xs = (unsigned short*)(w + fixedEnd);
        slots = (int*)(w + fixedEnd + xsBytes);
    }

    if (fast) {
        initxs_kernel<<<1024, 256, 0, stream>>>(x, Wm, b, gamma, beta, mean, var, Wt,
                                                scv, pov, deg, xs, N, N * 32);
        fill2_kernel<<<(E + 255) / 256, 256, 0, stream>>>(src, dst, deg, slots, E);
        dinv_kernel<<<(N + 255) / 256, 256, 0, stream>>>(deg, dinv, N);
        agg2_kernel<<<(N * 64 + 255) / 256, 256, 0, stream>>>(xs, dinv, deg, slots, src,
                                                              dst, out, N, E);
        int nTiles = (N + 15) / 16;
        gemm_kernel<<<(nTiles * 64 + 255) / 256, 256, 0, stream>>>(out, x, Wt, scv, pov,
                                                                   nTiles);
    } else {
        wt_kernel<<<(D * D) / 256, 256, 0, stream>>>(Wm, b, gamma, beta, mean, var, Wt,
                                                     scv, pov);
        hipMemsetAsync(deg, 0, sizeof(int) * N, stream);
        deg_kernel<<<(E + 255) / 256, 256, 0, stream>>>(dst, deg, E);
        dinv_kernel<<<(N + 255) / 256, 256, 0, stream>>>(deg, dinv, N);
        scan1_kernel<<<P, 256, 0, stream>>>(deg, bsum, N);
        scan2_kernel<<<1, 512, 0, stream>>>(bsum, offs, P, N);
        scan3_kernel<<<P, 256, 0, stream>>>(deg, bsum, offs, cursor, N);
        fill_kernel<<<(E + 255) / 256, 256, 0, stream>>>(src, dst, cursor, colidx, E);
        agg_kernel<<<(N * 64 + 255) / 256, 256, 0, stream>>>(x, dinv, offs, colidx, out,
                                                             N);
        int nTiles = (N + 15) / 16;
        gemm_kernel<<<(nTiles * 64 + 255) / 256, 256, 0, stream>>>(out, x, Wt, scv, pov,
                                                                   nTiles);
    }
}

// Round 8
// 303.534 us; speedup vs baseline: 1.5421x; 1.1756x over previous
//
#include <hip/hip_runtime.h>

#define D 128
#define BN_EPS 1e-5f
#define NBUCK 512     // coarse buckets, dst>>8 (391 used at N=100K), 256 nodes/bucket
#define BSHIFT 8
#define BNODES 256    // nodes per bucket

using short8 = __attribute__((ext_vector_type(8))) short;
using floatx4 = __attribute__((ext_vector_type(4))) float;

__device__ inline unsigned short f2bf(float f) {
    unsigned u = __float_as_uint(f);
    u += 0x7fff + ((u >> 16) & 1);  // RNE
    return (unsigned short)(u >> 16);
}
__device__ inline float bf2f(unsigned short s) {
    return __uint_as_float(((unsigned)s) << 16);
}

// ---------- wt: fallback-path only (fast path fuses this into pAwt) ----------
__global__ void wt_kernel(const float* __restrict__ W, const float* __restrict__ b,
                          const float* __restrict__ gamma, const float* __restrict__ beta,
                          const float* __restrict__ mean, const float* __restrict__ var,
                          unsigned short* __restrict__ Wt, float* __restrict__ scv,
                          float* __restrict__ pov) {
    int t = blockIdx.x * blockDim.x + threadIdx.x;
    int k = t >> 7, n = t & 127;
    Wt[(size_t)n * D + k] = f2bf(W[t]);
    if (t < D) {
        float sc = gamma[t] * rsqrtf(var[t] + BN_EPS);
        scv[t] = sc;
        pov[t] = (b[t] - mean[t]) * sc + beta[t];
    }
}

// ---------- pAwt: bucket histogram + fused Wt transpose / BN affine ----------
// All 1024 blocks histogram dst; blocks 0..15 additionally transpose W (2
// elements/thread); block 0 computes scv/pov. bucketTot pre-zeroed by memset.
__global__ __launch_bounds__(512) void pAwt_kernel(
    const int* __restrict__ dst, int* __restrict__ bucketTot, int E,
    const float* __restrict__ W, const float* __restrict__ b,
    const float* __restrict__ gamma, const float* __restrict__ beta,
    const float* __restrict__ mean, const float* __restrict__ var,
    unsigned short* __restrict__ Wt, float* __restrict__ scv,
    float* __restrict__ pov) {
    __shared__ int lh[NBUCK];
    int tid = threadIdx.x;
    lh[tid] = 0;
    __syncthreads();
    for (int i = blockIdx.x * 512 + tid; i < E; i += gridDim.x * 512)
        atomicAdd(&lh[dst[i] >> BSHIFT], 1);
    if (blockIdx.x < 16) {
        int t = blockIdx.x * 512 + tid;  // 0..8191
#pragma unroll
        for (int h = 0; h < 2; ++h) {
            int tt = t + h * 8192;
            Wt[(size_t)(tt & 127) * D + (tt >> 7)] = f2bf(W[tt]);
        }
        if (blockIdx.x == 0 && tid < D) {
            float sc = gamma[tid] * rsqrtf(var[tid] + BN_EPS);
            scv[tid] = sc;
            pov[tid] = (b[tid] - mean[tid]) * sc + beta[tid];
        }
    }
    __syncthreads();
    if (lh[tid]) atomicAdd(&bucketTot[tid], lh[tid]);
}

// ---------- pB: partition into bucket order (self-scanned bases) ----------
// 128 blocks: chunk = E/128 = ~12500 -> per-(block,bucket) runs ~24 edges
// (192B). Consecutive positions within a run make the pairs scatter mostly
// FULL-LINE writes (no read-allocate RMW) -- the fill2 counter analysis
// showed per-edge line-RMW costs ~130us; line-sized runs avoid it.
__global__ __launch_bounds__(512) void pB_kernel(const int* __restrict__ src,
                                                 const int* __restrict__ dst,
                                                 const int* __restrict__ bucketTot,
                                                 int* __restrict__ resCnt,
                                                 int2* __restrict__ pairs, int E) {
    __shared__ int sb[NBUCK];
    __shared__ int lh[NBUCK];
    __shared__ int lcur[NBUCK];
    int tid = threadIdx.x;
    sb[tid] = bucketTot[tid];
    lh[tid] = 0;
    __syncthreads();
    for (int d = 1; d < NBUCK; d <<= 1) {
        int v = (tid >= d) ? sb[tid - d] : 0;
        __syncthreads();
        sb[tid] += v;
        __syncthreads();
    }
    // sb = inclusive scan; exclusive base for bucket t = sb[t] - bucketTot[t]
    int chunk = (E + gridDim.x - 1) / gridDim.x;
    int base = blockIdx.x * chunk;
    int lim = min(chunk, E - base);
    if (lim <= 0) return;
    for (int i = tid; i < lim; i += 512) atomicAdd(&lh[dst[base + i] >> BSHIFT], 1);
    __syncthreads();
    int c = lh[tid];
    lcur[tid] = c ? (sb[tid] - bucketTot[tid]) + atomicAdd(&resCnt[tid], c) : 0;
    __syncthreads();
    for (int i = tid; i < lim; i += 512) {
        int s = src[base + i], d2 = dst[base + i];
        int pos = atomicAdd(&lcur[d2 >> BSHIFT], 1);
        pairs[pos] = make_int2(s, d2);
    }
}

// ---------- sortxs: within-bucket counting sort + fused xs/dinv build ----------
// One block per bucket (BNODES=256 nodes). deg is computed block-locally, so
// the xs conversion (x * dinv -> bf16) for this bucket's nodes fuses here.
__global__ __launch_bounds__(512) void sortxs_kernel(
    const int2* __restrict__ pairs, const int* __restrict__ bucketTot,
    const float* __restrict__ x, int* __restrict__ deg, int* __restrict__ offs,
    int* __restrict__ colidx, float* __restrict__ dinv,
    unsigned short* __restrict__ xs, int N, int E) {
    __shared__ int sb[NBUCK];
    __shared__ int lh[BNODES];
    __shared__ int lcur[BNODES];
    __shared__ float sdv[BNODES];
    int tid = threadIdx.x;
    int b = blockIdx.x;
    sb[tid] = bucketTot[tid];
    __syncthreads();
    for (int d = 1; d < NBUCK; d <<= 1) {
        int v = (tid >= d) ? sb[tid - d] : 0;
        __syncthreads();
        sb[tid] += v;
        __syncthreads();
    }
    int cnt = bucketTot[b];
    int base = sb[b] - cnt;  // exclusive bucket base
    if (tid < BNODES) lh[tid] = 0;
    __syncthreads();
    for (int i = tid; i < cnt; i += 512)
        atomicAdd(&lh[pairs[base + i].y & (BNODES - 1)], 1);
    __syncthreads();
    int orig = (tid < BNODES) ? lh[tid] : 0;
    for (int d = 1; d < BNODES; d <<= 1) {
        int v = (tid < BNODES && tid >= d) ? lh[tid - d] : 0;
        __syncthreads();
        if (tid < BNODES) lh[tid] += v;
        __syncthreads();
    }
    if (tid < BNODES) {
        int exc = lh[tid] - orig;
        int node = b * BNODES + tid;
        float dvv = rsqrtf((float)(orig + 1));
        sdv[tid] = dvv;
        if (node < N) {
            deg[node] = orig;
            offs[node] = base + exc;
            dinv[node] = dvv;
        }
        lcur[tid] = exc;
    }
    if (b == 0 && tid == 0) offs[N] = E;
    __syncthreads();
    // scatter colidx (grouped by dst within this bucket's ~12.5KB window)
    for (int i = tid; i < cnt; i += 512) {
        int2 p = pairs[base + i];
        int pos = atomicAdd(&lcur[p.y & (BNODES - 1)], 1);
        colidx[base + pos] = p.x;
    }
    // xs build for this bucket's nodes (sdv valid since the barrier above)
    int nb = min(BNODES, N - b * BNODES);
    if (nb > 0) {
        const float4* x4 = (const float4*)x;
        ushort4* xs4 = (ushort4*)xs;
        int tot = nb * 32;  // 32 float4 chunks per node
        for (int c = tid; c < tot; c += 512) {
            int nl = c >> 5, q = c & 31;
            int node = b * BNODES + nl;
            float dvv = sdv[nl];
            float4 f = x4[(size_t)node * 32 + q];
            ushort4 o;
            o.x = f2bf(dvv * f.x); o.y = f2bf(dvv * f.y);
            o.z = f2bf(dvv * f.z); o.w = f2bf(dvv * f.w);
            xs4[(size_t)node * 32 + q] = o;
        }
    }
}

// ---------- fallback kernels (small-ws path) ----------
__global__ void deg_kernel(const int* __restrict__ dst, int* __restrict__ deg, int E) {
    int e = blockIdx.x * blockDim.x + threadIdx.x;
    if (e < E) atomicAdd(&deg[dst[e]], 1);
}

__global__ void dinv_kernel(const int* __restrict__ deg, float* __restrict__ dinv, int N) {
    int v = blockIdx.x * blockDim.x + threadIdx.x;
    if (v < N) dinv[v] = rsqrtf((float)(deg[v] + 1));
}

__global__ __launch_bounds__(256) void scan1_kernel(const int* __restrict__ deg,
                                                    int* __restrict__ bsum, int N) {
    __shared__ int s[256];
    int t = threadIdx.x;
    int v = blockIdx.x * 256 + t;
    s[t] = (v < N) ? deg[v] : 0;
    for (int st = 128; st > 0; st >>= 1) {
        __syncthreads();
        if (t < st) s[t] += s[t + st];
    }
    if (t == 0) bsum[blockIdx.x] = s[0];
}

__global__ __launch_bounds__(512) void scan2_kernel(int* __restrict__ bsum,
                                                    int* __restrict__ offs, int P, int N) {
    __shared__ int a[512];
    int t = threadIdx.x;
    int orig = (t < P) ? bsum[t] : 0;
    a[t] = orig;
    __syncthreads();
    for (int d = 1; d < 512; d <<= 1) {
        int tv = (t >= d) ? a[t - d] : 0;
        __syncthreads();
        a[t] += tv;
        __syncthreads();
    }
    if (t < P) bsum[t] = a[t] - orig;
    if (t == 0) offs[N] = a[511];
}

__global__ __launch_bounds__(256) void scan3_kernel(const int* __restrict__ deg,
                                                    const int* __restrict__ bsum,
                                                    int* __restrict__ offs,
                                                    int* __restrict__ cursor, int N) {
    __shared__ int a[256];
    int t = threadIdx.x;
    int v = blockIdx.x * 256 + t;
    int d = (v < N) ? deg[v] : 0;
    a[t] = d;
    __syncthreads();
    for (int st = 1; st < 256; st <<= 1) {
        int tv = (t >= st) ? a[t - st] : 0;
        __syncthreads();
        a[t] += tv;
        __syncthreads();
    }
    if (v < N) {
        int off = bsum[blockIdx.x] + a[t] - d;
        offs[v] = off;
        cursor[v] = off;
    }
}

__global__ void fill_kernel(const int* __restrict__ src, const int* __restrict__ dst,
                            int* __restrict__ cursor, int* __restrict__ colidx, int E) {
    int e = blockIdx.x * blockDim.x + threadIdx.x;
    if (e < E) {
        int d = dst[e];
        int pos = atomicAdd(&cursor[d], 1);
        colidx[pos] = src[e];
    }
}

// ---------- gather-aggregate: one wave/node, lane = 2 packed cols ----------
// colidx/aggb are stream-once -> nontemporal, preserving L2 for the xs
// gather working set (25.6MB vs 4MB/XCD L2; every line helps). The 16-deep
// batch keeps colidx latency off the critical path.
__global__ __launch_bounds__(256) void agg_kernel(
    const float* __restrict__ x, const unsigned short* __restrict__ xs,
    const float* __restrict__ dinv, const int* __restrict__ offs,
    const int* __restrict__ colidx, float* __restrict__ outp,
    unsigned int* __restrict__ aggb, int N) {
    int wid = (blockIdx.x * blockDim.x + threadIdx.x) >> 6;
    if (wid >= N) return;
    int lane = threadIdx.x & 63;
    float dv = dinv[wid];
    float a0, a1;
    int p = offs[wid], pe = offs[wid + 1];
    if (xs) {
        const unsigned int* xs32 = (const unsigned int*)xs;
        unsigned int sv = xs32[(size_t)wid * 64 + lane];
        a0 = bf2f((unsigned short)sv);
        a1 = bf2f((unsigned short)(sv >> 16));
        for (; p + 16 <= pe; p += 16) {
            int u[16];
            unsigned int v[16];
#pragma unroll
            for (int j = 0; j < 16; ++j) u[j] = __builtin_nontemporal_load(colidx + p + j);
#pragma unroll
            for (int j = 0; j < 16; ++j) v[j] = xs32[(size_t)u[j] * 64 + lane];
#pragma unroll
            for (int j = 0; j < 16; ++j) {
                a0 += bf2f((unsigned short)v[j]);
                a1 += bf2f((unsigned short)(v[j] >> 16));
            }
        }
        for (; p + 4 <= pe; p += 4) {
            int u[4];
            unsigned int v[4];
#pragma unroll
            for (int j = 0; j < 4; ++j) u[j] = __builtin_nontemporal_load(colidx + p + j);
#pragma unroll
            for (int j = 0; j < 4; ++j) v[j] = xs32[(size_t)u[j] * 64 + lane];
#pragma unroll
            for (int j = 0; j < 4; ++j) {
                a0 += bf2f((unsigned short)v[j]);
                a1 += bf2f((unsigned short)(v[j] >> 16));
            }
        }
        for (; p < pe; ++p) {
            unsigned int v = xs32[(size_t)__builtin_nontemporal_load(colidx + p) * 64 + lane];
            a0 += bf2f((unsigned short)v);
            a1 += bf2f((unsigned short)(v >> 16));
        }
        __builtin_nontemporal_store(
            (unsigned int)f2bf(dv * a0) | ((unsigned int)f2bf(dv * a1) << 16),
            aggb + (size_t)wid * 64 + lane);
    } else {
        const float2* x2 = (const float2*)x;
        float2 s = x2[(size_t)wid * 64 + lane];
        a0 = dv * s.x;
        a1 = dv * s.y;
        for (; p < pe; ++p) {
            int u = colidx[p];
            float du = dinv[u];
            float2 vv = x2[(size_t)u * 64 + lane];
            a0 += du * vv.x;
            a1 += du * vv.y;
        }
        float2 r;
        r.x = dv * a0;
        r.y = dv * a1;
        ((float2*)outp)[(size_t)wid * 64 + lane] = r;
    }
}

// ---------- MFMA GEMM: out = relu(BN(agg @ W + b)) + x ----------
// Wt staged once per block in LDS (32KB), XOR-swizzled -> conflict-free
// ds_read_b128 B-fragments. aggb/xg/out are stream-once -> nontemporal.
__global__ __launch_bounds__(256) void gemm_kernel(
    float* __restrict__ outp, const float* __restrict__ xg,
    const unsigned short* __restrict__ Wt, const unsigned short* __restrict__ aggb,
    const float* __restrict__ scv, const float* __restrict__ pov, int nTiles) {
    __shared__ uint4 sW4[2048];  // 32KB: [row 0..127][c4 0..15] swizzled c4^=(row&7)
    int tid = threadIdx.x;
    const uint4* W4 = (const uint4*)Wt;
#pragma unroll
    for (int i = 0; i < 8; ++i) {
        int q = tid + i * 256;  // uint4 index 0..2047
        int row = q >> 4, c4 = q & 15;
        sW4[row * 16 + (c4 ^ (row & 7))] = W4[q];
    }
    __syncthreads();

    int wid = (blockIdx.x * blockDim.x + tid) >> 6;
    if (wid >= nTiles) return;
    int lane = tid & 63;
    int m = lane & 15, quad = lane >> 4;
    int row0 = wid * 16;

    short8 A[4];
    if (aggb) {
        const unsigned short* arow = aggb + (size_t)(row0 + m) * D;
#pragma unroll
        for (int ks = 0; ks < 4; ++ks)
            A[ks] = __builtin_nontemporal_load((const short8*)&arow[ks * 32 + quad * 8]);
    } else {
        const float* arow = outp + (size_t)(row0 + m) * D;
#pragma unroll
        for (int ks = 0; ks < 4; ++ks) {
            float4 f0 = *(const float4*)(arow + ks * 32 + quad * 8);
            float4 f1 = *(const float4*)(arow + ks * 32 + quad * 8 + 4);
            short8 af;
            af[0] = (short)f2bf(f0.x); af[1] = (short)f2bf(f0.y);
            af[2] = (short)f2bf(f0.z); af[3] = (short)f2bf(f0.w);
            af[4] = (short)f2bf(f1.x); af[5] = (short)f2bf(f1.y);
            af[6] = (short)f2bf(f1.z); af[7] = (short)f2bf(f1.w);
            A[ks] = af;
        }
    }

#pragma unroll
    for (int cg2 = 0; cg2 < 8; ++cg2) {
        int brow = cg2 * 16 + m;
        floatx4 acc = {0.f, 0.f, 0.f, 0.f};
#pragma unroll
        for (int ks = 0; ks < 4; ++ks) {
            short8 Bf = *(const short8*)&sW4[brow * 16 + ((ks * 4 + quad) ^ (m & 7))];
            acc = __builtin_amdgcn_mfma_f32_16x16x32_bf16(A[ks], Bf, acc, 0, 0, 0);
        }
        int col = cg2 * 16 + m;
        float sc = scv[col], po = pov[col];
#pragma unroll
        for (int i = 0; i < 4; ++i) {
            int row = row0 + quad * 4 + i;
            float bn = acc[i] * sc + po;
            size_t idx = (size_t)row * D + col;
            float xr = __builtin_nontemporal_load(xg + idx);
            __builtin_nontemporal_store(fmaxf(bn, 0.f) + xr, outp + idx);
        }
    }
}

extern "C" void kernel_launch(void* const* d_in, const int* in_sizes, int n_in,
                              void* d_out, int out_size, void* d_ws, size_t ws_size,
                              hipStream_t stream) {
    const float* x = (const float*)d_in[0];
    const int* edge = (const int*)d_in[1];
    const float* Wm = (const float*)d_in[2];
    const float* b = (const float*)d_in[3];
    const float* gamma = (const float*)d_in[4];
    const float* beta = (const float*)d_in[5];
    const float* mean = (const float*)d_in[6];
    const float* var = (const float*)d_in[7];
    float* out = (float*)d_out;

    int N = in_sizes[0] / D;
    int E = in_sizes[1] / 2;
    const int* src = edge;
    const int* dst = edge + E;
    int P = (N + 255) / 256;

    // ---- workspace layout ----
    char* w = (char*)d_ws;
    size_t cur = 0;
    auto take = [&](size_t bytes) -> void* {
        cur = (cur + 15) & ~(size_t)15;
        void* p = w + cur;
        cur += bytes;
        return p;
    };
    int* deg = (int*)take((size_t)N * 4);
    int* bucketTot = (int*)take(NBUCK * 4);
    int* resCnt = (int*)take(NBUCK * 4);  // contiguous with bucketTot (one memset)
    float* dinv = (float*)take((size_t)N * 4);
    int* offs = (int*)take((size_t)(N + 1) * 4);
    int* cursor = (int*)take((size_t)N * 4);
    int* bsum = (int*)take((size_t)(P + 1) * 4);
    unsigned short* Wt = (unsigned short*)take((size_t)D * D * 2);
    float* scv = (float*)take(D * 4);
    float* pov = (float*)take(D * 4);
    int* colidx = (int*)take((size_t)E * 4);
    cur = (cur + 15) & ~(size_t)15;
    size_t fixedEnd = cur;

    size_t xsBytes = (size_t)N * D * 2;
    size_t zoneBytes = (xsBytes > (size_t)E * 8) ? xsBytes : (size_t)E * 8;
    bool fast = fixedEnd + xsBytes + zoneBytes <= ws_size;

    unsigned short* xs = nullptr;
    int2* pairs = nullptr;
    unsigned int* aggb = nullptr;
    if (fast) {
        xs = (unsigned short*)(w + fixedEnd);
        pairs = (int2*)(w + fixedEnd + xsBytes);        // dead after sortxs_kernel
        aggb = (unsigned int*)(w + fixedEnd + xsBytes); // aliases pairs
    }

    if (fast) {
        hipMemsetAsync(bucketTot, 0, (size_t)NBUCK * 8, stream);  // bucketTot+resCnt
        pAwt_kernel<<<1024, 512, 0, stream>>>(dst, bucketTot, E, Wm, b, gamma, beta,
                                              mean, var, Wt, scv, pov);
        pB_kernel<<<128, 512, 0, stream>>>(src, dst, bucketTot, resCnt, pairs, E);
        sortxs_kernel<<<NBUCK, 512, 0, stream>>>(pairs, bucketTot, x, deg, offs, colidx,
                                                 dinv, xs, N, E);
        agg_kernel<<<(N * 64 + 255) / 256, 256, 0, stream>>>(x, xs, dinv, offs, colidx,
                                                             out, aggb, N);
        int nTiles = (N + 15) / 16;
        gemm_kernel<<<(nTiles * 64 + 255) / 256, 256, 0, stream>>>(
            out, x, Wt, (const unsigned short*)aggb, scv, pov, nTiles);
    } else {
        wt_kernel<<<(D * D) / 256, 256, 0, stream>>>(Wm, b, gamma, beta, mean, var, Wt,
                                                     scv, pov);
        hipMemsetAsync(deg, 0, sizeof(int) * N, stream);
        deg_kernel<<<(E + 255) / 256, 256, 0, stream>>>(dst, deg, E);
        dinv_kernel<<<(N + 255) / 256, 256, 0, stream>>>(deg, dinv, N);
        scan1_kernel<<<P, 256, 0, stream>>>(deg, bsum, N);
        scan2_kernel<<<1, 512, 0, stream>>>(bsum, offs, P, N);
        scan3_kernel<<<P, 256, 0, stream>>>(deg, bsum, offs, cursor, N);
        fill_kernel<<<(E + 255) / 256, 256, 0, stream>>>(src, dst, cursor, colidx, E);
        agg_kernel<<<(N * 64 + 255) / 256, 256, 0, stream>>>(x, nullptr, dinv, offs,
                                                             colidx, out, nullptr, N);
        int nTiles = (N + 15) / 16;
        gemm_kernel<<<(nTiles * 64 + 255) / 256, 256, 0, stream>>>(out, x, Wt, nullptr,
                                                                   scv, pov, nTiles);
    }
}

// Round 9
// 263.801 us; speedup vs baseline: 1.7744x; 1.1506x over previous
//
#include <hip/hip_runtime.h>

#define D 128
#define BN_EPS 1e-5f
#define NBUCK 512     // coarse buckets, dst>>8 (391 used at N=100K), 256 nodes/bucket
#define BSHIFT 8
#define BNODES 256    // nodes per bucket
#define CAP 4608      // padded slots/bucket; mean fill 4096 (+8 sigma)

using short8 = __attribute__((ext_vector_type(8))) short;
using floatx4 = __attribute__((ext_vector_type(4))) float;

__device__ inline unsigned short f2bf(float f) {
    unsigned u = __float_as_uint(f);
    u += 0x7fff + ((u >> 16) & 1);  // RNE
    return (unsigned short)(u >> 16);
}
__device__ inline float bf2f(unsigned short s) {
    return __uint_as_float(((unsigned)s) << 16);
}

// ---------- init: zero resCnt + Wt transpose + BN affine (tiny, 1 node) ----
__global__ __launch_bounds__(256) void init_kernel(
    const float* __restrict__ W, const float* __restrict__ b,
    const float* __restrict__ gamma, const float* __restrict__ beta,
    const float* __restrict__ mean, const float* __restrict__ var,
    unsigned short* __restrict__ Wt, float* __restrict__ scv,
    float* __restrict__ pov, int* __restrict__ resCnt) {
    int t = blockIdx.x * 256 + threadIdx.x;  // 0..16383 == D*D
    Wt[(size_t)(t & 127) * D + (t >> 7)] = f2bf(W[t]);
    if (t < NBUCK) resCnt[t] = 0;
    if (t < D) {
        float sc = gamma[t] * rsqrtf(var[t] + BN_EPS);
        scv[t] = sc;
        pov[t] = (b[t] - mean[t]) * sc + beta[t];
    }
}

// ---------- pB: partition into CAPACITY-PADDED buckets (no histogram!) ----
// 128 blocks: chunk ~12500 -> per-(block,bucket) runs ~32 edges x 4B = one
// full 128B line -> no read-allocate RMW (the R7-measured scatter wall).
// pairs entry = (dst&255)<<24 | src  (valid: N < 2^24). Base for a run is
// bucket*CAP + atomicAdd(resCnt) -- no global scan needed. Overflow edges
// (resCnt>CAP, ~impossible) are dropped here and recovered in sortxs/agg.
__global__ __launch_bounds__(512) void pB_kernel(const int* __restrict__ src,
                                                 const int* __restrict__ dst,
                                                 int* __restrict__ resCnt,
                                                 unsigned int* __restrict__ pairs,
                                                 int E) {
    __shared__ int lh[NBUCK];
    __shared__ int lcur[NBUCK];
    int tid = threadIdx.x;
    lh[tid] = 0;
    __syncthreads();
    int chunk = (E + gridDim.x - 1) / gridDim.x;
    int base = blockIdx.x * chunk;
    int lim = min(chunk, E - base);
    if (lim <= 0) return;
    for (int i = tid; i < lim; i += 512) atomicAdd(&lh[dst[base + i] >> BSHIFT], 1);
    __syncthreads();
    int c = lh[tid];
    lcur[tid] = tid * CAP + (c ? atomicAdd(&resCnt[tid], c) : 0);
    __syncthreads();
    for (int i = tid; i < lim; i += 512) {
        int s = src[base + i], d2 = dst[base + i];
        int b2 = d2 >> BSHIFT;
        int pos = atomicAdd(&lcur[b2], 1);
        if (pos < (b2 + 1) * CAP)
            pairs[pos] = (((unsigned)d2 & 255u) << 24) | (unsigned)s;
    }
}

// ---------- sortxs: per-bucket counting sort + premult xs build ----------
// Compact colidx bases come from a 512-wide LDS scan of resCnt (2KB, L2-hot)
// so colidx stays E-sized and the ws footprint == proven R4 layout.
// Overflow bucket (cnt>CAP): offs=-1 marker, deg/dinv from full edge scan.
__global__ __launch_bounds__(512) void sortxs_kernel(
    const unsigned int* __restrict__ pairs, const int* __restrict__ resCnt,
    const int* __restrict__ src, const int* __restrict__ dst,
    const float* __restrict__ x, int* __restrict__ deg, int* __restrict__ offs,
    int* __restrict__ colidx, float* __restrict__ dinv,
    unsigned short* __restrict__ xs, int N, int E) {
    __shared__ int sb[NBUCK];
    __shared__ int lh[BNODES];
    __shared__ int lcur[BNODES];
    __shared__ float sdv[BNODES];
    int tid = threadIdx.x;
    int b = blockIdx.x;
    sb[tid] = resCnt[tid];
    __syncthreads();
    for (int d = 1; d < NBUCK; d <<= 1) {
        int v = (tid >= d) ? sb[tid - d] : 0;
        __syncthreads();
        sb[tid] += v;
        __syncthreads();
    }
    int cnt = resCnt[b];
    int cbase = sb[b] - cnt;       // compact colidx base
    int pbase = b * CAP;           // padded pairs base
    if (tid < BNODES) lh[tid] = 0;
    __syncthreads();

    if (cnt <= CAP) {
        // ---- normal path ----
        for (int i = tid; i < cnt; i += 512)
            atomicAdd(&lh[pairs[pbase + i] >> 24], 1);
        __syncthreads();
        int orig = (tid < BNODES) ? lh[tid] : 0;
        for (int d = 1; d < BNODES; d <<= 1) {
            int v = (tid < BNODES && tid >= d) ? lh[tid - d] : 0;
            __syncthreads();
            if (tid < BNODES) lh[tid] += v;
            __syncthreads();
        }
        if (tid < BNODES) {
            int exc = lh[tid] - orig;
            int node = b * BNODES + tid;
            float dvv = rsqrtf((float)(orig + 1));
            sdv[tid] = dvv;
            if (node < N) {
                deg[node] = orig;
                offs[node] = cbase + exc;
                dinv[node] = dvv;
            }
            lcur[tid] = exc;
        }
        __syncthreads();
        for (int i = tid; i < cnt; i += 512) {
            unsigned int p = pairs[pbase + i];
            int pos = atomicAdd(&lcur[p >> 24], 1);
            colidx[cbase + pos] = (int)(p & 0x00FFFFFFu);
        }
    } else {
        // ---- overflow recovery: exact deg from full edge scan; no colidx ----
        for (int i = tid; i < E; i += 512) {
            int d2 = dst[i];
            if ((d2 >> BSHIFT) == b) atomicAdd(&lh[d2 & 255], 1);
        }
        __syncthreads();
        if (tid < BNODES) {
            int orig = lh[tid];
            int node = b * BNODES + tid;
            float dvv = rsqrtf((float)(orig + 1));
            sdv[tid] = dvv;
            if (node < N) {
                deg[node] = orig;
                offs[node] = -1;  // agg falls back to full scan for this node
                dinv[node] = dvv;
            }
        }
        __syncthreads();
    }

    // ---- xs build for this bucket's nodes: xs = bf16(dinv[n] * x[n]) ----
    int nb = min(BNODES, N - b * BNODES);
    if (nb > 0) {
        const float4* x4 = (const float4*)x;
        ushort4* xs4 = (ushort4*)xs;
        int tot = nb * 32;  // 32 float4 chunks per node
        for (int c2 = tid; c2 < tot; c2 += 512) {
            int nl = c2 >> 5, q = c2 & 31;
            int node = b * BNODES + nl;
            float dvv = sdv[nl];
            float4 f = x4[(size_t)node * 32 + q];
            ushort4 o;
            o.x = f2bf(dvv * f.x); o.y = f2bf(dvv * f.y);
            o.z = f2bf(dvv * f.z); o.w = f2bf(dvv * f.w);
            xs4[(size_t)node * 32 + q] = o;
        }
    }
}

// ---------- fallback kernels (small-ws path) ----------
__global__ void wt_kernel(const float* __restrict__ W, const float* __restrict__ b,
                          const float* __restrict__ gamma, const float* __restrict__ beta,
                          const float* __restrict__ mean, const float* __restrict__ var,
                          unsigned short* __restrict__ Wt, float* __restrict__ scv,
                          float* __restrict__ pov) {
    int t = blockIdx.x * blockDim.x + threadIdx.x;
    int k = t >> 7, n = t & 127;
    Wt[(size_t)n * D + k] = f2bf(W[t]);
    if (t < D) {
        float sc = gamma[t] * rsqrtf(var[t] + BN_EPS);
        scv[t] = sc;
        pov[t] = (b[t] - mean[t]) * sc + beta[t];
    }
}

__global__ void deg_kernel(const int* __restrict__ dst, int* __restrict__ deg, int E) {
    int e = blockIdx.x * blockDim.x + threadIdx.x;
    if (e < E) atomicAdd(&deg[dst[e]], 1);
}

__global__ void dinv_kernel(const int* __restrict__ deg, float* __restrict__ dinv, int N) {
    int v = blockIdx.x * blockDim.x + threadIdx.x;
    if (v < N) dinv[v] = rsqrtf((float)(deg[v] + 1));
}

__global__ __launch_bounds__(256) void scan1_kernel(const int* __restrict__ deg,
                                                    int* __restrict__ bsum, int N) {
    __shared__ int s[256];
    int t = threadIdx.x;
    int v = blockIdx.x * 256 + t;
    s[t] = (v < N) ? deg[v] : 0;
    for (int st = 128; st > 0; st >>= 1) {
        __syncthreads();
        if (t < st) s[t] += s[t + st];
    }
    if (t == 0) bsum[blockIdx.x] = s[0];
}

__global__ __launch_bounds__(512) void scan2_kernel(int* __restrict__ bsum,
                                                    int* __restrict__ offs, int P, int N) {
    __shared__ int a[512];
    int t = threadIdx.x;
    int orig = (t < P) ? bsum[t] : 0;
    a[t] = orig;
    __syncthreads();
    for (int d = 1; d < 512; d <<= 1) {
        int tv = (t >= d) ? a[t - d] : 0;
        __syncthreads();
        a[t] += tv;
        __syncthreads();
    }
    if (t < P) bsum[t] = a[t] - orig;
    if (t == 0) offs[N] = a[511];
}

__global__ __launch_bounds__(256) void scan3_kernel(const int* __restrict__ deg,
                                                    const int* __restrict__ bsum,
                                                    int* __restrict__ offs,
                                                    int* __restrict__ cursor, int N) {
    __shared__ int a[256];
    int t = threadIdx.x;
    int v = blockIdx.x * 256 + t;
    int d = (v < N) ? deg[v] : 0;
    a[t] = d;
    __syncthreads();
    for (int st = 1; st < 256; st <<= 1) {
        int tv = (t >= st) ? a[t - st] : 0;
        __syncthreads();
        a[t] += tv;
        __syncthreads();
    }
    if (v < N) {
        int off = bsum[blockIdx.x] + a[t] - d;
        offs[v] = off;
        cursor[v] = off;
    }
}

__global__ void fill_kernel(const int* __restrict__ src, const int* __restrict__ dst,
                            int* __restrict__ cursor, int* __restrict__ colidx, int E) {
    int e = blockIdx.x * blockDim.x + threadIdx.x;
    if (e < E) {
        int d = dst[e];
        int pos = atomicAdd(&cursor[d], 1);
        colidx[pos] = src[e];
    }
}

// ---------- gather-aggregate: one wave/node, lane = 2 packed cols ----------
// R4-proven body; pe = offs + deg (supports overflow marker offs<0).
__global__ __launch_bounds__(256) void agg_kernel(
    const float* __restrict__ x, const unsigned short* __restrict__ xs,
    const float* __restrict__ dinv, const int* __restrict__ offs,
    const int* __restrict__ deg, const int* __restrict__ colidx,
    const int* __restrict__ src, const int* __restrict__ dst,
    float* __restrict__ outp, unsigned int* __restrict__ aggb, int N, int E) {
    int wid = (blockIdx.x * blockDim.x + threadIdx.x) >> 6;
    if (wid >= N) return;
    int lane = threadIdx.x & 63;
    float dv = dinv[wid];
    float a0, a1;
    int p = offs[wid];
    if (xs) {
        const unsigned int* xs32 = (const unsigned int*)xs;
        unsigned int sv = xs32[(size_t)wid * 64 + lane];
        a0 = bf2f((unsigned short)sv);
        a1 = bf2f((unsigned short)(sv >> 16));
        if (p >= 0) {
            int pe = p + deg[wid];
            for (; p + 16 <= pe; p += 16) {
                int u[16];
                unsigned int v[16];
#pragma unroll
                for (int j = 0; j < 16; ++j) u[j] = colidx[p + j];
#pragma unroll
                for (int j = 0; j < 16; ++j) v[j] = xs32[(size_t)u[j] * 64 + lane];
#pragma unroll
                for (int j = 0; j < 16; ++j) {
                    a0 += bf2f((unsigned short)v[j]);
                    a1 += bf2f((unsigned short)(v[j] >> 16));
                }
            }
            for (; p + 4 <= pe; p += 4) {
                int u[4];
                unsigned int v[4];
#pragma unroll
                for (int j = 0; j < 4; ++j) u[j] = colidx[p + j];
#pragma unroll
                for (int j = 0; j < 4; ++j) v[j] = xs32[(size_t)u[j] * 64 + lane];
#pragma unroll
                for (int j = 0; j < 4; ++j) {
                    a0 += bf2f((unsigned short)v[j]);
                    a1 += bf2f((unsigned short)(v[j] >> 16));
                }
            }
            for (; p < pe; ++p) {
                unsigned int v = xs32[(size_t)colidx[p] * 64 + lane];
                a0 += bf2f((unsigned short)v);
                a1 += bf2f((unsigned short)(v >> 16));
            }
        } else {
            // overflow-bucket node: gather via full edge scan (never on bench)
            for (int e = 0; e < E; ++e) {
                if (dst[e] == wid) {
                    unsigned int v = xs32[(size_t)src[e] * 64 + lane];
                    a0 += bf2f((unsigned short)v);
                    a1 += bf2f((unsigned short)(v >> 16));
                }
            }
        }
        aggb[(size_t)wid * 64 + lane] =
            (unsigned int)f2bf(dv * a0) | ((unsigned int)f2bf(dv * a1) << 16);
    } else {
        const float2* x2 = (const float2*)x;
        float2 s = x2[(size_t)wid * 64 + lane];
        a0 = dv * s.x;
        a1 = dv * s.y;
        int pe = p + deg[wid];
        for (; p < pe; ++p) {
            int u = colidx[p];
            float du = dinv[u];
            float2 vv = x2[(size_t)u * 64 + lane];
            a0 += du * vv.x;
            a1 += du * vv.y;
        }
        float2 r;
        r.x = dv * a0;
        r.y = dv * a1;
        ((float2*)outp)[(size_t)wid * 64 + lane] = r;
    }
}

// ---------- MFMA GEMM: out = relu(BN(agg @ W + b)) + x (R4 body, no nt) ----
__global__ __launch_bounds__(256) void gemm_kernel(
    float* __restrict__ outp, const float* __restrict__ xg,
    const unsigned short* __restrict__ Wt, const unsigned short* __restrict__ aggb,
    const float* __restrict__ scv, const float* __restrict__ pov, int nTiles) {
    __shared__ uint4 sW4[2048];  // 32KB: [row 0..127][c4 0..15] swizzled c4^=(row&7)
    int tid = threadIdx.x;
    const uint4* W4 = (const uint4*)Wt;
#pragma unroll
    for (int i = 0; i < 8; ++i) {
        int q = tid + i * 256;  // uint4 index 0..2047
        int row = q >> 4, c4 = q & 15;
        sW4[row * 16 + (c4 ^ (row & 7))] = W4[q];
    }
    __syncthreads();

    int wid = (blockIdx.x * blockDim.x + tid) >> 6;
    if (wid >= nTiles) return;
    int lane = tid & 63;
    int m = lane & 15, quad = lane >> 4;
    int row0 = wid * 16;

    short8 A[4];
    if (aggb) {
        const unsigned short* arow = aggb + (size_t)(row0 + m) * D;
#pragma unroll
        for (int ks = 0; ks < 4; ++ks)
            A[ks] = *(const short8*)&arow[ks * 32 + quad * 8];
    } else {
        const float* arow = outp + (size_t)(row0 + m) * D;
#pragma unroll
        for (int ks = 0; ks < 4; ++ks) {
            float4 f0 = *(const float4*)(arow + ks * 32 + quad * 8);
            float4 f1 = *(const float4*)(arow + ks * 32 + quad * 8 + 4);
            short8 af;
            af[0] = (short)f2bf(f0.x); af[1] = (short)f2bf(f0.y);
            af[2] = (short)f2bf(f0.z); af[3] = (short)f2bf(f0.w);
            af[4] = (short)f2bf(f1.x); af[5] = (short)f2bf(f1.y);
            af[6] = (short)f2bf(f1.z); af[7] = (short)f2bf(f1.w);
            A[ks] = af;
        }
    }

#pragma unroll
    for (int cg2 = 0; cg2 < 8; ++cg2) {
        int brow = cg2 * 16 + m;
        floatx4 acc = {0.f, 0.f, 0.f, 0.f};
#pragma unroll
        for (int ks = 0; ks < 4; ++ks) {
            short8 Bf = *(const short8*)&sW4[brow * 16 + ((ks * 4 + quad) ^ (m & 7))];
            acc = __builtin_amdgcn_mfma_f32_16x16x32_bf16(A[ks], Bf, acc, 0, 0, 0);
        }
        int col = cg2 * 16 + m;
        float sc = scv[col], po = pov[col];
#pragma unroll
        for (int i = 0; i < 4; ++i) {
            int row = row0 + quad * 4 + i;
            float bn = acc[i] * sc + po;
            size_t idx = (size_t)row * D + col;
            outp[idx] = fmaxf(bn, 0.f) + xg[idx];
        }
    }
}

extern "C" void kernel_launch(void* const* d_in, const int* in_sizes, int n_in,
                              void* d_out, int out_size, void* d_ws, size_t ws_size,
                              hipStream_t stream) {
    const float* x = (const float*)d_in[0];
    const int* edge = (const int*)d_in[1];
    const float* Wm = (const float*)d_in[2];
    const float* b = (const float*)d_in[3];
    const float* gamma = (const float*)d_in[4];
    const float* beta = (const float*)d_in[5];
    const float* mean = (const float*)d_in[6];
    const float* var = (const float*)d_in[7];
    float* out = (float*)d_out;

    int N = in_sizes[0] / D;
    int E = in_sizes[1] / 2;
    const int* src = edge;
    const int* dst = edge + E;
    int P = (N + 255) / 256;

    // ---- workspace layout (fixed area identical to proven R4 footprint) ----
    char* w = (char*)d_ws;
    size_t cur = 0;
    auto take = [&](size_t bytes) -> void* {
        cur = (cur + 15) & ~(size_t)15;
        void* p = w + cur;
        cur += bytes;
        return p;
    };
    int* deg = (int*)take((size_t)N * 4);
    int* resCnt = (int*)take(NBUCK * 4);
    float* dinv = (float*)take((size_t)N * 4);
    int* offs = (int*)take((size_t)(N + 1) * 4);
    int* cursor = (int*)take((size_t)N * 4);
    int* bsum = (int*)take((size_t)(P + 1) * 4);
    unsigned short* Wt = (unsigned short*)take((size_t)D * D * 2);
    float* scv = (float*)take(D * 4);
    float* pov = (float*)take(D * 4);
    int* colidx = (int*)take((size_t)E * 4);
    cur = (cur + 15) & ~(size_t)15;
    size_t fixedEnd = cur;

    size_t xsBytes = (size_t)N * D * 2;
    size_t pairsBytes = (size_t)NBUCK * CAP * 4;  // padded packed-u32 pairs
    size_t zoneBytes = (xsBytes > pairsBytes) ? xsBytes : pairsBytes;
    bool fast = (fixedEnd + xsBytes + zoneBytes <= ws_size) && (N < (1 << 24));

    unsigned short* xs = nullptr;
    unsigned int* pairs = nullptr;
    unsigned int* aggb = nullptr;
    if (fast) {
        xs = (unsigned short*)(w + fixedEnd);
        pairs = (unsigned int*)(w + fixedEnd + xsBytes);  // dead after sortxs
        aggb = (unsigned int*)(w + fixedEnd + xsBytes);   // aliases pairs
    }

    if (fast) {
        init_kernel<<<(D * D) / 256, 256, 0, stream>>>(Wm, b, gamma, beta, mean, var,
                                                       Wt, scv, pov, resCnt);
        pB_kernel<<<128, 512, 0, stream>>>(src, dst, resCnt, pairs, E);
        sortxs_kernel<<<NBUCK, 512, 0, stream>>>(pairs, resCnt, src, dst, x, deg, offs,
                                                 colidx, dinv, xs, N, E);
        agg_kernel<<<(N * 64 + 255) / 256, 256, 0, stream>>>(
            x, xs, dinv, offs, deg, colidx, src, dst, out, aggb, N, E);
        int nTiles = (N + 15) / 16;
        gemm_kernel<<<(nTiles * 64 + 255) / 256, 256, 0, stream>>>(
            out, x, Wt, (const unsigned short*)aggb, scv, pov, nTiles);
    } else {
        wt_kernel<<<(D * D) / 256, 256, 0, stream>>>(Wm, b, gamma, beta, mean, var, Wt,
                                                     scv, pov);
        hipMemsetAsync(deg, 0, sizeof(int) * N, stream);
        deg_kernel<<<(E + 255) / 256, 256, 0, stream>>>(dst, deg, E);
        dinv_kernel<<<(N + 255) / 256, 256, 0, stream>>>(deg, dinv, N);
        scan1_kernel<<<P, 256, 0, stream>>>(deg, bsum, N);
        scan2_kernel<<<1, 512, 0, stream>>>(bsum, offs, P, N);
        scan3_kernel<<<P, 256, 0, stream>>>(deg, bsum, offs, cursor, N);
        fill_kernel<<<(E + 255) / 256, 256, 0, stream>>>(src, dst, cursor, colidx, E);
        agg_kernel<<<(N * 64 + 255) / 256, 256, 0, stream>>>(
            x, nullptr, dinv, offs, deg, colidx, src, dst, out, nullptr, N, E);
        int nTiles = (N + 15) / 16;
        gemm_kernel<<<(nTiles * 64 + 255) / 256, 256, 0, stream>>>(out, x, Wt, nullptr,
                                                                   scv, pov, nTiles);
    }
}